// Round 1
// baseline (177.222 us; speedup 1.0000x reference)
//
#include <hip/hip_runtime.h>

typedef __attribute__((ext_vector_type(8))) short short8;
typedef __attribute__((ext_vector_type(4))) float f32x4;

#define MFMA(a,b,c) __builtin_amdgcn_mfma_f32_16x16x32_bf16((a),(b),(c),0,0,0)

#define B_  2
#define S_  2048
#define D_  1024
#define H_  16
#define DK  64
#define KDIM 1024

typedef unsigned int u32;
typedef __attribute__((address_space(1))) const u32 gu32;
typedef __attribute__((address_space(3))) u32 lu32;

// async global->LDS, 16 B per lane; LDS dest = base + lane*16 (wave-uniform base)
__device__ __forceinline__ void gll16(const unsigned short* g, unsigned short* l){
  __builtin_amdgcn_global_load_lds((gu32*)g, (lu32*)l, 16, 0, 0);
}

__device__ __forceinline__ unsigned short f2bf(float f){
  unsigned int u = __float_as_uint(f);
  u += 0x7fffu + ((u >> 16) & 1u);   // RNE (finite inputs only)
  return (unsigned short)(u >> 16);
}

// pack two f32 -> two bf16 (round-half-up) in 3 VALU: 2 adds + v_perm_b32.
__device__ __forceinline__ u32 pkbf(float lo, float hi){
  u32 a = __float_as_uint(lo) + 0x8000u;
  u32 b = __float_as_uint(hi) + 0x8000u;
  return __builtin_amdgcn_perm(b, a, 0x07060302u);
}

// ---------------- fp32 -> bf16 convert, all 5 tensors in one launch ---------
__global__ void cvt_all(const float* __restrict__ x,  const float* __restrict__ qw,
                        const float* __restrict__ kw, const float* __restrict__ vw,
                        const float* __restrict__ ow,
                        unsigned short* __restrict__ xb,  unsigned short* __restrict__ wqb,
                        unsigned short* __restrict__ wkb, unsigned short* __restrict__ wvb,
                        unsigned short* __restrict__ wob,
                        int n4x, int n4w){
  int i = blockIdx.x * 256 + threadIdx.x;
  const float* src; unsigned short* dst; int n4;
  switch (blockIdx.y) {
    case 0:  src = x;  dst = xb;  n4 = n4x; break;
    case 1:  src = qw; dst = wqb; n4 = n4w; break;
    case 2:  src = kw; dst = wkb; n4 = n4w; break;
    case 3:  src = vw; dst = wvb; n4 = n4w; break;
    default: src = ow; dst = wob; n4 = n4w; break;
  }
  if (i >= n4) return;
  float4 f = reinterpret_cast<const float4*>(src)[i];
  ushort4 u;
  u.x = f2bf(f.x); u.y = f2bf(f.y); u.z = f2bf(f.z); u.w = f2bf(f.w);
  reinterpret_cast<ushort4*>(dst)[i] = u;
}

// ---------------- fused QKV projection (m97 128x128 structure) --------------
// C[m,n] = sum_k X[m,k] * W[n,k];  z=0 -> Q (scaled); z=1 -> K; z=2 -> V^T.
// LDS tiles [128][64] shorts (128 B rows). T2-style chunk-rotation swizzle:
// physical 16B chunk p of row r holds logical chunk (p ^ (r&7)).  Done the
// rule-21 way: linear global_load_lds dest + inverse-swizzled GLOBAL source
// + swizzled ds_read.  Read-side XOR is a per-thread constant since the
// fragment row step (16) is 0 mod 8.
// Batch-issue staging, ONE drain per 64-K window (interleaved prefetch
// regressed twice on this problem: compute C << latency L).
__global__ __launch_bounds__(256) void gemm_qkv(
    const unsigned short* __restrict__ X,
    const unsigned short* __restrict__ Wq,
    const unsigned short* __restrict__ Wk,
    const unsigned short* __restrict__ Wv,
    unsigned short* __restrict__ Qo,
    unsigned short* __restrict__ Ko,
    unsigned short* __restrict__ Vo)
{
  const int z = blockIdx.z;
  const unsigned short* __restrict__ W = (z == 0) ? Wq : (z == 1) ? Wk : Wv;
  const int n0 = blockIdx.x * 128;
  const int m0 = blockIdx.y * 128;

  __shared__ unsigned short As[128 * 64];
  __shared__ unsigned short Bs[128 * 64];

  const int tid  = threadIdx.x;
  const int wid  = tid >> 6, lane = tid & 63;
  const int wm   = (wid >> 1) * 64, wn = (wid & 1) * 64;
  const int lr   = lane & 15, c = lane >> 4;       // frag row / 16B chunk grp
  const int sw   = lr & 7;
  const int pc0  = (c ^ sw) * 8;                   // k-half 0 chunk, shorts
  const int pc1  = ((4 + c) ^ sw) * 8;             // k-half 1 chunk, shorts

  // staging: each gll16 fills 8 rows x 128 B linearly; lane l writes row
  // (l>>3), physical chunk (l&7) -> fetch logical chunk (l&7)^(row&7).
  const int srow = lane >> 3;                      // 0..7
  const int scol = ((lane & 7) ^ srow) * 8;        // shorts
  const unsigned short* gA = X + (size_t)(m0 + wid * 32 + srow) * KDIM + scol;
  const unsigned short* gB = W + (size_t)(n0 + wid * 32 + srow) * KDIM + scol;
  unsigned short* lA = &As[(wid * 32) * 64];
  unsigned short* lB = &Bs[(wid * 32) * 64];

  f32x4 acc[4][4];
  const f32x4 z4 = {0.f, 0.f, 0.f, 0.f};
  for (int i = 0; i < 4; i++)
    for (int j = 0; j < 4; j++) acc[i][j] = z4;

  for (int k0 = 0; k0 < KDIM; k0 += 64) {
    __syncthreads();
#pragma unroll
    for (int i = 0; i < 4; i++) gll16(gA + (size_t)(i * 8) * KDIM + k0, lA + i * 512);
#pragma unroll
    for (int i = 0; i < 4; i++) gll16(gB + (size_t)(i * 8) * KDIM + k0, lB + i * 512);
    __syncthreads();

    short8 a[4], b[4];
    // k-half 0
#pragma unroll
    for (int i = 0; i < 4; i++) a[i] = *(const short8*)&As[(wm + i * 16 + lr) * 64 + pc0];
#pragma unroll
    for (int j = 0; j < 4; j++) b[j] = *(const short8*)&Bs[(wn + j * 16 + lr) * 64 + pc0];
    if (z == 2) {
#pragma unroll
      for (int i = 0; i < 4; i++)
#pragma unroll
        for (int j = 0; j < 4; j++)
          acc[i][j] = MFMA(b[j], a[i], acc[i][j]);   // rows=W-dim, cols=X-dim
    } else {
#pragma unroll
      for (int i = 0; i < 4; i++)
#pragma unroll
        for (int j = 0; j < 4; j++)
          acc[i][j] = MFMA(a[i], b[j], acc[i][j]);
    }
    // k-half 1
#pragma unroll
    for (int i = 0; i < 4; i++) a[i] = *(const short8*)&As[(wm + i * 16 + lr) * 64 + pc1];
#pragma unroll
    for (int j = 0; j < 4; j++) b[j] = *(const short8*)&Bs[(wn + j * 16 + lr) * 64 + pc1];
    if (z == 2) {
#pragma unroll
      for (int i = 0; i < 4; i++)
#pragma unroll
        for (int j = 0; j < 4; j++)
          acc[i][j] = MFMA(b[j], a[i], acc[i][j]);
    } else {
#pragma unroll
      for (int i = 0; i < 4; i++)
#pragma unroll
        for (int j = 0; j < 4; j++)
          acc[i][j] = MFMA(a[i], b[j], acc[i][j]);
    }
  }

  const int rbase = (lane >> 4) * 4;
  if (z == 2) {
    for (int i = 0; i < 4; i++)
      for (int j = 0; j < 4; j++)
        for (int r = 0; r < 4; r++) {
          int dfull = n0 + wn + j * 16 + rbase + r;   // W row (h,dk)
          int sfull = m0 + wm + i * 16 + lr;          // X row (b,s)
          int h = dfull >> 6, d = dfull & 63;
          int bb = sfull >> 11, s = sfull & 2047;
          Vo[(((bb * H_ + h) * DK) + d) * S_ + s] = f2bf(acc[i][j][r]);
        }
  } else {
    for (int i = 0; i < 4; i++)
      for (int j = 0; j < 4; j++)
        for (int r = 0; r < 4; r++) {
          int m = m0 + wm + i * 16 + rbase + r;
          int n = n0 + wn + j * 16 + lr;
          float v = acc[i][j][r];
          int bb = m >> 11, s = m & 2047, h = n >> 6, d = n & 63;
          if (z == 0) {
            v *= 0.18033688f;  // (1/sqrt(64)) * log2(e): softmax in exp2 domain
            Qo[(((bb * H_ + h) * S_) + s) * DK + d] = f2bf(v);
          } else {
            Ko[(((bb * H_ + h) * S_) + s) * DK + d] = f2bf(v);
          }
        }
  }
}

// ---------------- causal flash attention (R9 structure, kept) ---------------
// Q,K: [B,H,S,DK] bf16 (Q pre-scaled to exp2 domain); V: [B,H,DK,S] bf16.
// K/V staged via global_load_lds into UNPADDED 64x64 tiles with a rotation
// swizzle: physical 16B-chunk c of row r holds logical chunk (c-r)&7.
// Ping-pong buffers, 1 barrier per tile, no reg round-trip.
__global__ __launch_bounds__(512, 4) void attn(
    const unsigned short* __restrict__ Q,
    const unsigned short* __restrict__ K,
    const unsigned short* __restrict__ V,
    unsigned short* __restrict__ O)
{
  const int h = blockIdx.y, b = blockIdx.z;
  const int qt = b ? (15 - blockIdx.x) : blockIdx.x;

  const unsigned short* __restrict__ Qh = Q + (size_t)((b * H_ + h) * S_) * DK;
  const unsigned short* __restrict__ Kh = K + (size_t)((b * H_ + h) * S_) * DK;
  const unsigned short* __restrict__ Vh = V + (size_t)((b * H_ + h) * DK) * S_;

  __shared__ unsigned short Ks0[64 * 64];     // [key][d], swizzled chunks
  __shared__ unsigned short Ks1[64 * 64];
  __shared__ unsigned short Vs0[64 * 64];     // [d][key], swizzled chunks
  __shared__ unsigned short Vs1[64 * 64];
  __shared__ unsigned short Ps[8][16][72];    // per-wave: [q][key] (padded)

  const int tid = threadIdx.x, wid = tid >> 6, lane = tid & 63;
  const int lr = lane & 15;
  const int row4 = (lane >> 4) * 4;
  const int q0 = qt * 128;
  const int qcol = q0 + wid * 16 + lr;
  const int qwmin = q0 + wid * 16;
  const int qwmax = qwmin + 15;
  const int lk = (lane >> 4) * 8;             // for Q/P fragments (unswizzled)

  // swizzled LDS read offsets (shorts): logical chunk q=(lane>>4), rot by row
  const int pc0 = (((lane >> 4) + lr) & 7) * 8;
  const int pc1 = (((lane >> 4) + 4 + lr) & 7) * 8;

  // staging: wave wid covers rows [8*wid, 8*wid+8) of both K and V tiles
  const int sr8 = lane >> 3;                  // 0..7 row within chunk
  const int sc8 = lane & 7;                   // physical chunk
  const int sg  = (sc8 - sr8) & 7;            // logical chunk to fetch
  const int stRow = wid * 8 + sr8;            // 0..63
  const unsigned short* gK = Kh + (size_t)stRow * DK + sg * 8;
  const unsigned short* gV = Vh + (size_t)stRow * S_ + sg * 8;
  unsigned short* lK0 = &Ks0[wid * 8 * 64];
  unsigned short* lK1 = &Ks1[wid * 8 * 64];
  unsigned short* lV0 = &Vs0[wid * 8 * 64];
  unsigned short* lV1 = &Vs1[wid * 8 * 64];

  const short ONE = (short)0x3F80;            // bf16 1.0
  const short8 ones = {ONE, ONE, ONE, ONE, ONE, ONE, ONE, ONE};

  short8 qf[2];
  qf[0] = *(const short8*)&Qh[(q0 + wid * 16 + lr) * DK + lk];
  qf[1] = *(const short8*)&Qh[(q0 + wid * 16 + lr) * DK + 32 + lk];

  const f32x4 z4 = {0.f, 0.f, 0.f, 0.f};
  f32x4 o[4];
  for (int i = 0; i < 4; i++) o[i] = z4;
  f32x4 rs = z4;                              // l(q=lr) on the MFMA pipe

  auto tile = [&](int k0, const unsigned short* KS, const unsigned short* VS){
    if (k0 > qwmax) return;                   // wave-uniform skip
    f32x4 sc[4];
    for (int nt = 0; nt < 4; nt++) {
      short8 kb0 = *(const short8*)&KS[(nt * 16 + lr) * 64 + pc0];
      short8 kb1 = *(const short8*)&KS[(nt * 16 + lr) * 64 + pc1];
      f32x4 s = MFMA(kb0, qf[0], z4);
      sc[nt] = MFMA(kb1, qf[1], s);
    }
    if (k0 + 63 > qwmin) {                    // diagonal region: mask key > q
      for (int nt = 0; nt < 4; nt++) {
        int kg = k0 + nt * 16 + row4;
        for (int r = 0; r < 4; r++)
          if (kg + r > qcol) sc[nt][r] = -INFINITY;
      }
    }
    for (int nt = 0; nt < 4; nt++) {
      float p0 = __builtin_amdgcn_exp2f(sc[nt][0]);
      float p1 = __builtin_amdgcn_exp2f(sc[nt][1]);
      float p2 = __builtin_amdgcn_exp2f(sc[nt][2]);
      float p3 = __builtin_amdgcn_exp2f(sc[nt][3]);
      uint2 pk;
      pk.x = pkbf(p0, p1);
      pk.y = pkbf(p2, p3);
      *(uint2*)&Ps[wid][lr][nt * 16 + row4] = pk;
    }
    short8 pf0 = *(const short8*)&Ps[wid][lr][lk];
    short8 pf1 = *(const short8*)&Ps[wid][lr][32 + lk];
    rs = MFMA(ones, pf0, rs);
    rs = MFMA(ones, pf1, rs);
    for (int dt = 0; dt < 4; dt++) {
      short8 vb0 = *(const short8*)&VS[(dt * 16 + lr) * 64 + pc0];
      short8 vb1 = *(const short8*)&VS[(dt * 16 + lr) * 64 + pc1];
      o[dt] = MFMA(vb0, pf0, o[dt]);
      o[dt] = MFMA(vb1, pf1, o[dt]);
    }
  };

  const int kt_end = 2 * qt + 2;              // even

  // prologue: tile 0 into buf0
  gll16(gK, lK0);
  gll16(gV, lV0);

  for (int kt = 0; kt < kt_end; kt += 2) {
    const int k0 = kt * 64;
    __syncthreads();                          // buf0 (k0) ready
    {                                         // kt+1 always < kt_end
      gll16(gK + (size_t)(k0 + 64) * DK, lK1);
      gll16(gV + (k0 + 64),              lV1);
    }
    tile(k0, Ks0, Vs0);
    __syncthreads();                          // buf1 (k0+64) ready
    if (kt + 2 < kt_end) {
      gll16(gK + (size_t)(k0 + 128) * DK, lK0);
      gll16(gV + (k0 + 128),              lV0);
    }
    tile(k0 + 64, Ks1, Vs1);
  }

  const float inv = 1.0f / rs[0];

  const int srow = q0 + wid * 16 + lr;
  for (int dt = 0; dt < 4; dt++) {
    uint2 pk;
    pk.x = pkbf(o[dt][0] * inv, o[dt][1] * inv);
    pk.y = pkbf(o[dt][2] * inv, o[dt][3] * inv);
    *(uint2*)&O[(size_t)(b * S_ + srow) * D_ + h * DK + dt * 16 + row4] = pk;
  }
}

// ---------------- output projection (m97 128x128 structure, fp32 out) -------
__global__ __launch_bounds__(256) void gemm_oproj(
    const unsigned short* __restrict__ A,
    const unsigned short* __restrict__ W,
    float* __restrict__ out)
{
  const int n0 = blockIdx.x * 128;
  const int m0 = blockIdx.y * 128;

  __shared__ unsigned short As[128 * 64];
  __shared__ unsigned short Bs[128 * 64];

  const int tid  = threadIdx.x;
  const int wid  = tid >> 6, lane = tid & 63;
  const int wm   = (wid >> 1) * 64, wn = (wid & 1) * 64;
  const int lr   = lane & 15, c = lane >> 4;
  const int sw   = lr & 7;
  const int pc0  = (c ^ sw) * 8;
  const int pc1  = ((4 + c) ^ sw) * 8;

  const int srow = lane >> 3;
  const int scol = ((lane & 7) ^ srow) * 8;
  const unsigned short* gA = A + (size_t)(m0 + wid * 32 + srow) * KDIM + scol;
  const unsigned short* gB = W + (size_t)(n0 + wid * 32 + srow) * KDIM + scol;
  unsigned short* lA = &As[(wid * 32) * 64];
  unsigned short* lB = &Bs[(wid * 32) * 64];

  f32x4 acc[4][4];
  const f32x4 z4 = {0.f, 0.f, 0.f, 0.f};
  for (int i = 0; i < 4; i++)
    for (int j = 0; j < 4; j++) acc[i][j] = z4;

  for (int k0 = 0; k0 < KDIM; k0 += 64) {
    __syncthreads();
#pragma unroll
    for (int i = 0; i < 4; i++) gll16(gA + (size_t)(i * 8) * KDIM + k0, lA + i * 512);
#pragma unroll
    for (int i = 0; i < 4; i++) gll16(gB + (size_t)(i * 8) * KDIM + k0, lB + i * 512);
    __syncthreads();

    short8 a[4], b[4];
#pragma unroll
    for (int i = 0; i < 4; i++) a[i] = *(const short8*)&As[(wm + i * 16 + lr) * 64 + pc0];
#pragma unroll
    for (int j = 0; j < 4; j++) b[j] = *(const short8*)&Bs[(wn + j * 16 + lr) * 64 + pc0];
#pragma unroll
    for (int i = 0; i < 4; i++)
#pragma unroll
      for (int j = 0; j < 4; j++)
        acc[i][j] = MFMA(a[i], b[j], acc[i][j]);
#pragma unroll
    for (int i = 0; i < 4; i++) a[i] = *(const short8*)&As[(wm + i * 16 + lr) * 64 + pc1];
#pragma unroll
    for (int j = 0; j < 4; j++) b[j] = *(const short8*)&Bs[(wn + j * 16 + lr) * 64 + pc1];
#pragma unroll
    for (int i = 0; i < 4; i++)
#pragma unroll
      for (int j = 0; j < 4; j++)
        acc[i][j] = MFMA(a[i], b[j], acc[i][j]);
  }

  const int rbase = (lane >> 4) * 4;
  for (int i = 0; i < 4; i++)
    for (int j = 0; j < 4; j++)
      for (int r = 0; r < 4; r++) {
        int m = m0 + wm + i * 16 + rbase + r;
        int n = n0 + wn + j * 16 + lr;
        out[(size_t)m * D_ + n] = acc[i][j][r];
      }
}

extern "C" void kernel_launch(void* const* d_in, const int* in_sizes, int n_in,
                              void* d_out, int out_size, void* d_ws, size_t ws_size,
                              hipStream_t stream) {
  const float* x  = (const float*)d_in[0];
  const float* qw = (const float*)d_in[1];
  const float* kw = (const float*)d_in[2];
  const float* vw = (const float*)d_in[3];
  const float* ow = (const float*)d_in[4];
  float* out = (float*)d_out;

  char* ws = (char*)d_ws;
  size_t off = 0;
  auto alloc = [&](size_t bytes) -> void* {
    void* p = ws + off;
    off += (bytes + 255) & ~(size_t)255;
    return p;
  };
  const size_t XN = (size_t)B_ * S_ * D_;     // 4194304
  const size_t WN = (size_t)D_ * D_;          // 1048576
  unsigned short* xb  = (unsigned short*)alloc(XN * 2);
  unsigned short* wqb = (unsigned short*)alloc(WN * 2);
  unsigned short* wkb = (unsigned short*)alloc(WN * 2);
  unsigned short* wvb = (unsigned short*)alloc(WN * 2);
  unsigned short* wob = (unsigned short*)alloc(WN * 2);
  unsigned short* Qb  = (unsigned short*)alloc(XN * 2);
  unsigned short* Kb  = (unsigned short*)alloc(XN * 2);
  unsigned short* Vb  = (unsigned short*)alloc(XN * 2);
  unsigned short* Ob  = (unsigned short*)alloc(XN * 2);

  cvt_all<<<dim3((XN / 4 + 255) / 256, 5), dim3(256), 0, stream>>>(
      x, qw, kw, vw, ow, xb, wqb, wkb, wvb, wob, (int)(XN / 4), (int)(WN / 4));

  gemm_qkv<<<dim3(D_ / 128, (B_ * S_) / 128, 3), dim3(256), 0, stream>>>(
      xb, wqb, wkb, wvb, Qb, Kb, Vb);

  attn<<<dim3(S_ / 128, H_, B_), dim3(512), 0, stream>>>(Qb, Kb, Vb, Ob);

  gemm_oproj<<<dim3(D_ / 128, (B_ * S_) / 128), dim3(256), 0, stream>>>(Ob, wob, out);
}

// Round 2
// 162.781 us; speedup vs baseline: 1.0887x; 1.0887x over previous
//
#include <hip/hip_runtime.h>

typedef __attribute__((ext_vector_type(8))) short short8;
typedef __attribute__((ext_vector_type(4))) float f32x4;

#define MFMA(a,b,c) __builtin_amdgcn_mfma_f32_16x16x32_bf16((a),(b),(c),0,0,0)

#define B_  2
#define S_  2048
#define D_  1024
#define H_  16
#define DK  64
#define KDIM 1024

typedef unsigned int u32;
typedef __attribute__((address_space(1))) const u32 gu32;
typedef __attribute__((address_space(3))) u32 lu32;

// async global->LDS, 16 B per lane; LDS dest = base + lane*16 (wave-uniform base)
__device__ __forceinline__ void gll16(const unsigned short* g, unsigned short* l){
  __builtin_amdgcn_global_load_lds((gu32*)g, (lu32*)l, 16, 0, 0);
}

__device__ __forceinline__ unsigned short f2bf(float f){
  unsigned int u = __float_as_uint(f);
  u += 0x7fffu + ((u >> 16) & 1u);   // RNE (finite inputs only)
  return (unsigned short)(u >> 16);
}

// pack two f32 -> two bf16 (round-half-up) in 3 VALU: 2 adds + v_perm_b32.
__device__ __forceinline__ u32 pkbf(float lo, float hi){
  u32 a = __float_as_uint(lo) + 0x8000u;
  u32 b = __float_as_uint(hi) + 0x8000u;
  return __builtin_amdgcn_perm(b, a, 0x07060302u);
}

// ---------------- fp32 -> bf16 convert, all 5 tensors in one launch ---------
__global__ void cvt_all(const float* __restrict__ x,  const float* __restrict__ qw,
                        const float* __restrict__ kw, const float* __restrict__ vw,
                        const float* __restrict__ ow,
                        unsigned short* __restrict__ xb,  unsigned short* __restrict__ wqb,
                        unsigned short* __restrict__ wkb, unsigned short* __restrict__ wvb,
                        unsigned short* __restrict__ wob,
                        int n4x, int n4w){
  int i = blockIdx.x * 256 + threadIdx.x;
  const float* src; unsigned short* dst; int n4;
  switch (blockIdx.y) {
    case 0:  src = x;  dst = xb;  n4 = n4x; break;
    case 1:  src = qw; dst = wqb; n4 = n4w; break;
    case 2:  src = kw; dst = wkb; n4 = n4w; break;
    case 3:  src = vw; dst = wvb; n4 = n4w; break;
    default: src = ow; dst = wob; n4 = n4w; break;
  }
  if (i >= n4) return;
  float4 f = reinterpret_cast<const float4*>(src)[i];
  ushort4 u;
  u.x = f2bf(f.x); u.y = f2bf(f.y); u.z = f2bf(f.z); u.w = f2bf(f.w);
  reinterpret_cast<ushort4*>(dst)[i] = u;
}

struct Frags { short8 a0[4], a1[4], b0[2], b1[2]; };

// ---------------- fused QKV projection (counted-vmcnt pipeline) -------------
// C[m,n] = sum_k X[m,k] * W[n,k];  z=0 -> Q (scaled); z=1 -> K; z=2 -> V^T.
// 128x64 tile, BK=64. LDS rows are 128 B with chunk-XOR swizzle (phys 16B
// chunk p of row r holds logical chunk p^(r&7)); swizzle applied rule-21
// style: linear global_load_lds dest + inverse-swizzled GLOBAL source +
// swizzled ds_read (per-lane constant XOR since fragment row step 16 == 0
// mod 8).  Verified conflict-free in R1 (SQ_LDS_BANK_CONFLICT = 0).
// Double-buffered, depth-2 counted vmcnt: per step wait vmcnt(6) (tile
// issued 2 steps ago), read frags, lgkmcnt(0)+barrier (buf free), issue
// stage(t+2) into same buf, MFMA.  No vmcnt(0) drain in steady state.
__global__ __launch_bounds__(256) void gemm_qkv(
    const unsigned short* __restrict__ X,
    const unsigned short* __restrict__ Wq,
    const unsigned short* __restrict__ Wk,
    const unsigned short* __restrict__ Wv,
    unsigned short* __restrict__ Qo,
    unsigned short* __restrict__ Ko,
    unsigned short* __restrict__ Vo)
{
  const int z = blockIdx.z;
  const unsigned short* __restrict__ W = (z == 0) ? Wq : (z == 1) ? Wk : Wv;
  const int n0 = blockIdx.x * 64;
  const int m0 = blockIdx.y * 128;

  __shared__ unsigned short As[2][128 * 64];   // 2 x 16 KiB
  __shared__ unsigned short Bs[2][64 * 64];    // 2 x  8 KiB

  const int tid  = threadIdx.x;
  const int wid  = tid >> 6, lane = tid & 63;
  const int wm   = (wid >> 1) * 64, wn = (wid & 1) * 32;
  const int lr   = lane & 15, c = lane >> 4;
  const int sw   = lr & 7;
  const int pc0  = (c ^ sw) * 8;               // k-half 0 chunk, shorts
  const int pc1  = ((c ^ 4) ^ sw) * 8;         // k-half 1 chunk, shorts

  const int srow = lane >> 3;                  // 0..7
  const int scol = ((lane & 7) ^ srow) * 8;    // inverse-swizzled source col
  const unsigned short* gA = X + (size_t)(m0 + wid * 32 + srow) * KDIM + scol;
  const unsigned short* gB = W + (size_t)(n0 + wid * 16 + srow) * KDIM + scol;

  auto stage = [&](int buf, int k0) {
    unsigned short* la = &As[buf][(wid * 32) * 64];
    unsigned short* lb = &Bs[buf][(wid * 16) * 64];
#pragma unroll
    for (int i = 0; i < 4; i++) gll16(gA + (size_t)(i * 8) * KDIM + k0, la + i * 512);
#pragma unroll
    for (int i = 0; i < 2; i++) gll16(gB + (size_t)(i * 8) * KDIM + k0, lb + i * 512);
  };

  auto ldfr = [&](int buf, Frags& f) {
    const unsigned short* AS = As[buf];
    const unsigned short* BS = Bs[buf];
#pragma unroll
    for (int i = 0; i < 4; i++) {
      f.a0[i] = *(const short8*)&AS[(wm + i * 16 + lr) * 64 + pc0];
      f.a1[i] = *(const short8*)&AS[(wm + i * 16 + lr) * 64 + pc1];
    }
#pragma unroll
    for (int j = 0; j < 2; j++) {
      f.b0[j] = *(const short8*)&BS[(wn + j * 16 + lr) * 64 + pc0];
      f.b1[j] = *(const short8*)&BS[(wn + j * 16 + lr) * 64 + pc1];
    }
  };

  f32x4 acc[4][2];
  const f32x4 z4 = {0.f, 0.f, 0.f, 0.f};
  for (int i = 0; i < 4; i++)
    for (int j = 0; j < 2; j++) acc[i][j] = z4;

  auto mfmas = [&](const Frags& f) {
    if (z == 2) {
#pragma unroll
      for (int i = 0; i < 4; i++)
#pragma unroll
        for (int j = 0; j < 2; j++) {
          acc[i][j] = MFMA(f.b0[j], f.a0[i], acc[i][j]);   // rows=W-dim, cols=X-dim
          acc[i][j] = MFMA(f.b1[j], f.a1[i], acc[i][j]);
        }
    } else {
#pragma unroll
      for (int i = 0; i < 4; i++)
#pragma unroll
        for (int j = 0; j < 2; j++) {
          acc[i][j] = MFMA(f.a0[i], f.b0[j], acc[i][j]);
          acc[i][j] = MFMA(f.a1[i], f.b1[j], acc[i][j]);
        }
    }
  };

  // prologue: two tiles in flight
  stage(0, 0);
  stage(1, 64);

  Frags f;
  const int NT = KDIM / 64;                    // 16
  for (int t = 0; t < NT - 2; ++t) {
    const int buf = t & 1;
    asm volatile("s_waitcnt vmcnt(6)" ::: "memory");   // my stage(t) landed
    __builtin_amdgcn_s_barrier();                       // everyone's landed
    asm volatile("" ::: "memory");
    ldfr(buf, f);
    asm volatile("s_waitcnt lgkmcnt(0)" ::: "memory"); // my reads serviced
    __builtin_amdgcn_sched_barrier(0);
    __builtin_amdgcn_s_barrier();                       // buf free to overwrite
    asm volatile("" ::: "memory");
    stage(buf, (t + 2) * 64);                           // 6 loads in flight
    __builtin_amdgcn_sched_barrier(0);
    mfmas(f);                                           // covers load latency
  }
  // t = NT-2: no further staging
  asm volatile("s_waitcnt vmcnt(6)" ::: "memory");
  __builtin_amdgcn_s_barrier();
  asm volatile("" ::: "memory");
  ldfr((NT - 2) & 1, f);
  mfmas(f);
  // t = NT-1: drain the last tile
  asm volatile("s_waitcnt vmcnt(0)" ::: "memory");
  __builtin_amdgcn_s_barrier();
  asm volatile("" ::: "memory");
  ldfr((NT - 1) & 1, f);
  mfmas(f);

  const int rbase = (lane >> 4) * 4;
  if (z == 2) {
    for (int i = 0; i < 4; i++)
      for (int j = 0; j < 2; j++)
        for (int r = 0; r < 4; r++) {
          int dfull = n0 + wn + j * 16 + rbase + r;   // W row (h,dk)
          int sfull = m0 + wm + i * 16 + lr;          // X row (b,s)
          int h = dfull >> 6, d = dfull & 63;
          int bb = sfull >> 11, s = sfull & 2047;
          Vo[(((bb * H_ + h) * DK) + d) * S_ + s] = f2bf(acc[i][j][r]);
        }
  } else {
    for (int i = 0; i < 4; i++)
      for (int j = 0; j < 2; j++)
        for (int r = 0; r < 4; r++) {
          int m = m0 + wm + i * 16 + rbase + r;
          int n = n0 + wn + j * 16 + lr;
          float v = acc[i][j][r];
          int bb = m >> 11, s = m & 2047, h = n >> 6, d = n & 63;
          if (z == 0) {
            v *= 0.18033688f;  // (1/sqrt(64)) * log2(e): softmax in exp2 domain
            Qo[(((bb * H_ + h) * S_) + s) * DK + d] = f2bf(v);
          } else {
            Ko[(((bb * H_ + h) * S_) + s) * DK + d] = f2bf(v);
          }
        }
  }
}

// ---------------- causal flash attention (R9 structure, kept) ---------------
// Q,K: [B,H,S,DK] bf16 (Q pre-scaled to exp2 domain); V: [B,H,DK,S] bf16.
// K/V staged via global_load_lds into UNPADDED 64x64 tiles with a rotation
// swizzle: physical 16B-chunk c of row r holds logical chunk (c-r)&7.
// Ping-pong buffers, 1 barrier per tile, no reg round-trip.
__global__ __launch_bounds__(512, 4) void attn(
    const unsigned short* __restrict__ Q,
    const unsigned short* __restrict__ K,
    const unsigned short* __restrict__ V,
    unsigned short* __restrict__ O)
{
  const int h = blockIdx.y, b = blockIdx.z;
  const int qt = b ? (15 - blockIdx.x) : blockIdx.x;

  const unsigned short* __restrict__ Qh = Q + (size_t)((b * H_ + h) * S_) * DK;
  const unsigned short* __restrict__ Kh = K + (size_t)((b * H_ + h) * S_) * DK;
  const unsigned short* __restrict__ Vh = V + (size_t)((b * H_ + h) * DK) * S_;

  __shared__ unsigned short Ks0[64 * 64];     // [key][d], swizzled chunks
  __shared__ unsigned short Ks1[64 * 64];
  __shared__ unsigned short Vs0[64 * 64];     // [d][key], swizzled chunks
  __shared__ unsigned short Vs1[64 * 64];
  __shared__ unsigned short Ps[8][16][72];    // per-wave: [q][key] (padded)

  const int tid = threadIdx.x, wid = tid >> 6, lane = tid & 63;
  const int lr = lane & 15;
  const int row4 = (lane >> 4) * 4;
  const int q0 = qt * 128;
  const int qcol = q0 + wid * 16 + lr;
  const int qwmin = q0 + wid * 16;
  const int qwmax = qwmin + 15;
  const int lk = (lane >> 4) * 8;             // for Q/P fragments (unswizzled)

  // swizzled LDS read offsets (shorts): logical chunk q=(lane>>4), rot by row
  const int pc0 = (((lane >> 4) + lr) & 7) * 8;
  const int pc1 = (((lane >> 4) + 4 + lr) & 7) * 8;

  // staging: wave wid covers rows [8*wid, 8*wid+8) of both K and V tiles
  const int sr8 = lane >> 3;                  // 0..7 row within chunk
  const int sc8 = lane & 7;                   // physical chunk
  const int sg  = (sc8 - sr8) & 7;            // logical chunk to fetch
  const int stRow = wid * 8 + sr8;            // 0..63
  const unsigned short* gK = Kh + (size_t)stRow * DK + sg * 8;
  const unsigned short* gV = Vh + (size_t)stRow * S_ + sg * 8;
  unsigned short* lK0 = &Ks0[wid * 8 * 64];
  unsigned short* lK1 = &Ks1[wid * 8 * 64];
  unsigned short* lV0 = &Vs0[wid * 8 * 64];
  unsigned short* lV1 = &Vs1[wid * 8 * 64];

  const short ONE = (short)0x3F80;            // bf16 1.0
  const short8 ones = {ONE, ONE, ONE, ONE, ONE, ONE, ONE, ONE};

  short8 qf[2];
  qf[0] = *(const short8*)&Qh[(q0 + wid * 16 + lr) * DK + lk];
  qf[1] = *(const short8*)&Qh[(q0 + wid * 16 + lr) * DK + 32 + lk];

  const f32x4 z4 = {0.f, 0.f, 0.f, 0.f};
  f32x4 o[4];
  for (int i = 0; i < 4; i++) o[i] = z4;
  f32x4 rs = z4;                              // l(q=lr) on the MFMA pipe

  auto tile = [&](int k0, const unsigned short* KS, const unsigned short* VS){
    if (k0 > qwmax) return;                   // wave-uniform skip
    f32x4 sc[4];
    for (int nt = 0; nt < 4; nt++) {
      short8 kb0 = *(const short8*)&KS[(nt * 16 + lr) * 64 + pc0];
      short8 kb1 = *(const short8*)&KS[(nt * 16 + lr) * 64 + pc1];
      f32x4 s = MFMA(kb0, qf[0], z4);
      sc[nt] = MFMA(kb1, qf[1], s);
    }
    if (k0 + 63 > qwmin) {                    // diagonal region: mask key > q
      for (int nt = 0; nt < 4; nt++) {
        int kg = k0 + nt * 16 + row4;
        for (int r = 0; r < 4; r++)
          if (kg + r > qcol) sc[nt][r] = -INFINITY;
      }
    }
    for (int nt = 0; nt < 4; nt++) {
      float p0 = __builtin_amdgcn_exp2f(sc[nt][0]);
      float p1 = __builtin_amdgcn_exp2f(sc[nt][1]);
      float p2 = __builtin_amdgcn_exp2f(sc[nt][2]);
      float p3 = __builtin_amdgcn_exp2f(sc[nt][3]);
      uint2 pk;
      pk.x = pkbf(p0, p1);
      pk.y = pkbf(p2, p3);
      *(uint2*)&Ps[wid][lr][nt * 16 + row4] = pk;
    }
    short8 pf0 = *(const short8*)&Ps[wid][lr][lk];
    short8 pf1 = *(const short8*)&Ps[wid][lr][32 + lk];
    rs = MFMA(ones, pf0, rs);
    rs = MFMA(ones, pf1, rs);
    for (int dt = 0; dt < 4; dt++) {
      short8 vb0 = *(const short8*)&VS[(dt * 16 + lr) * 64 + pc0];
      short8 vb1 = *(const short8*)&VS[(dt * 16 + lr) * 64 + pc1];
      o[dt] = MFMA(vb0, pf0, o[dt]);
      o[dt] = MFMA(vb1, pf1, o[dt]);
    }
  };

  const int kt_end = 2 * qt + 2;              // even

  // prologue: tile 0 into buf0
  gll16(gK, lK0);
  gll16(gV, lV0);

  for (int kt = 0; kt < kt_end; kt += 2) {
    const int k0 = kt * 64;
    __syncthreads();                          // buf0 (k0) ready
    {                                         // kt+1 always < kt_end
      gll16(gK + (size_t)(k0 + 64) * DK, lK1);
      gll16(gV + (k0 + 64),              lV1);
    }
    tile(k0, Ks0, Vs0);
    __syncthreads();                          // buf1 (k0+64) ready
    if (kt + 2 < kt_end) {
      gll16(gK + (size_t)(k0 + 128) * DK, lK0);
      gll16(gV + (k0 + 128),              lV0);
    }
    tile(k0 + 64, Ks1, Vs1);
  }

  const float inv = 1.0f / rs[0];

  const int srow = q0 + wid * 16 + lr;
  for (int dt = 0; dt < 4; dt++) {
    uint2 pk;
    pk.x = pkbf(o[dt][0] * inv, o[dt][1] * inv);
    pk.y = pkbf(o[dt][2] * inv, o[dt][3] * inv);
    *(uint2*)&O[(size_t)(b * S_ + srow) * D_ + h * DK + dt * 16 + row4] = pk;
  }
}

// ---------------- output projection (counted-vmcnt pipeline, fp32 out) ------
__global__ __launch_bounds__(256) void gemm_oproj(
    const unsigned short* __restrict__ A,
    const unsigned short* __restrict__ W,
    float* __restrict__ out)
{
  const int n0 = blockIdx.x * 64;
  const int m0 = blockIdx.y * 128;

  __shared__ unsigned short As[2][128 * 64];
  __shared__ unsigned short Bs[2][64 * 64];

  const int tid  = threadIdx.x;
  const int wid  = tid >> 6, lane = tid & 63;
  const int wm   = (wid >> 1) * 64, wn = (wid & 1) * 32;
  const int lr   = lane & 15, c = lane >> 4;
  const int sw   = lr & 7;
  const int pc0  = (c ^ sw) * 8;
  const int pc1  = ((c ^ 4) ^ sw) * 8;

  const int srow = lane >> 3;
  const int scol = ((lane & 7) ^ srow) * 8;
  const unsigned short* gA = A + (size_t)(m0 + wid * 32 + srow) * KDIM + scol;
  const unsigned short* gB = W + (size_t)(n0 + wid * 16 + srow) * KDIM + scol;

  auto stage = [&](int buf, int k0) {
    unsigned short* la = &As[buf][(wid * 32) * 64];
    unsigned short* lb = &Bs[buf][(wid * 16) * 64];
#pragma unroll
    for (int i = 0; i < 4; i++) gll16(gA + (size_t)(i * 8) * KDIM + k0, la + i * 512);
#pragma unroll
    for (int i = 0; i < 2; i++) gll16(gB + (size_t)(i * 8) * KDIM + k0, lb + i * 512);
  };

  auto ldfr = [&](int buf, Frags& f) {
    const unsigned short* AS = As[buf];
    const unsigned short* BS = Bs[buf];
#pragma unroll
    for (int i = 0; i < 4; i++) {
      f.a0[i] = *(const short8*)&AS[(wm + i * 16 + lr) * 64 + pc0];
      f.a1[i] = *(const short8*)&AS[(wm + i * 16 + lr) * 64 + pc1];
    }
#pragma unroll
    for (int j = 0; j < 2; j++) {
      f.b0[j] = *(const short8*)&BS[(wn + j * 16 + lr) * 64 + pc0];
      f.b1[j] = *(const short8*)&BS[(wn + j * 16 + lr) * 64 + pc1];
    }
  };

  f32x4 acc[4][2];
  const f32x4 z4 = {0.f, 0.f, 0.f, 0.f};
  for (int i = 0; i < 4; i++)
    for (int j = 0; j < 2; j++) acc[i][j] = z4;

  auto mfmas = [&](const Frags& f) {
#pragma unroll
    for (int i = 0; i < 4; i++)
#pragma unroll
      for (int j = 0; j < 2; j++) {
        acc[i][j] = MFMA(f.a0[i], f.b0[j], acc[i][j]);
        acc[i][j] = MFMA(f.a1[i], f.b1[j], acc[i][j]);
      }
  };

  stage(0, 0);
  stage(1, 64);

  Frags f;
  const int NT = KDIM / 64;                    // 16
  for (int t = 0; t < NT - 2; ++t) {
    const int buf = t & 1;
    asm volatile("s_waitcnt vmcnt(6)" ::: "memory");
    __builtin_amdgcn_s_barrier();
    asm volatile("" ::: "memory");
    ldfr(buf, f);
    asm volatile("s_waitcnt lgkmcnt(0)" ::: "memory");
    __builtin_amdgcn_sched_barrier(0);
    __builtin_amdgcn_s_barrier();
    asm volatile("" ::: "memory");
    stage(buf, (t + 2) * 64);
    __builtin_amdgcn_sched_barrier(0);
    mfmas(f);
  }
  asm volatile("s_waitcnt vmcnt(6)" ::: "memory");
  __builtin_amdgcn_s_barrier();
  asm volatile("" ::: "memory");
  ldfr((NT - 2) & 1, f);
  mfmas(f);
  asm volatile("s_waitcnt vmcnt(0)" ::: "memory");
  __builtin_amdgcn_s_barrier();
  asm volatile("" ::: "memory");
  ldfr((NT - 1) & 1, f);
  mfmas(f);

  const int rbase = (lane >> 4) * 4;
  for (int i = 0; i < 4; i++)
    for (int j = 0; j < 2; j++)
      for (int r = 0; r < 4; r++) {
        int m = m0 + wm + i * 16 + rbase + r;
        int n = n0 + wn + j * 16 + lr;
        out[(size_t)m * D_ + n] = acc[i][j][r];
      }
}

extern "C" void kernel_launch(void* const* d_in, const int* in_sizes, int n_in,
                              void* d_out, int out_size, void* d_ws, size_t ws_size,
                              hipStream_t stream) {
  const float* x  = (const float*)d_in[0];
  const float* qw = (const float*)d_in[1];
  const float* kw = (const float*)d_in[2];
  const float* vw = (const float*)d_in[3];
  const float* ow = (const float*)d_in[4];
  float* out = (float*)d_out;

  char* ws = (char*)d_ws;
  size_t off = 0;
  auto alloc = [&](size_t bytes) -> void* {
    void* p = ws + off;
    off += (bytes + 255) & ~(size_t)255;
    return p;
  };
  const size_t XN = (size_t)B_ * S_ * D_;     // 4194304
  const size_t WN = (size_t)D_ * D_;          // 1048576
  unsigned short* xb  = (unsigned short*)alloc(XN * 2);
  unsigned short* wqb = (unsigned short*)alloc(WN * 2);
  unsigned short* wkb = (unsigned short*)alloc(WN * 2);
  unsigned short* wvb = (unsigned short*)alloc(WN * 2);
  unsigned short* wob = (unsigned short*)alloc(WN * 2);
  unsigned short* Qb  = (unsigned short*)alloc(XN * 2);
  unsigned short* Kb  = (unsigned short*)alloc(XN * 2);
  unsigned short* Vb  = (unsigned short*)alloc(XN * 2);
  unsigned short* Ob  = (unsigned short*)alloc(XN * 2);

  cvt_all<<<dim3((XN / 4 + 255) / 256, 5), dim3(256), 0, stream>>>(
      x, qw, kw, vw, ow, xb, wqb, wkb, wvb, wob, (int)(XN / 4), (int)(WN / 4));

  gemm_qkv<<<dim3(D_ / 64, (B_ * S_) / 128, 3), dim3(256), 0, stream>>>(
      xb, wqb, wkb, wvb, Qb, Kb, Vb);

  attn<<<dim3(S_ / 128, H_, B_), dim3(512), 0, stream>>>(Qb, Kb, Vb, Ob);

  gemm_oproj<<<dim3(D_ / 64, (B_ * S_) / 128), dim3(256), 0, stream>>>(Ob, wob, out);
}

// Round 3
// 152.584 us; speedup vs baseline: 1.1615x; 1.0668x over previous
//
#include <hip/hip_runtime.h>

typedef __attribute__((ext_vector_type(8))) short short8;
typedef __attribute__((ext_vector_type(4))) float f32x4;

#define MFMA(a,b,c) __builtin_amdgcn_mfma_f32_16x16x32_bf16((a),(b),(c),0,0,0)

#define B_  2
#define S_  2048
#define D_  1024
#define H_  16
#define DK  64
#define KDIM 1024

typedef unsigned int u32;
typedef __attribute__((address_space(1))) const u32 gu32;
typedef __attribute__((address_space(3))) u32 lu32;

// async global->LDS, 16 B per lane; LDS dest = base + lane*16 (wave-uniform base)
__device__ __forceinline__ void gll16(const unsigned short* g, unsigned short* l){
  __builtin_amdgcn_global_load_lds((gu32*)g, (lu32*)l, 16, 0, 0);
}

__device__ __forceinline__ unsigned short f2bf(float f){
  unsigned int u = __float_as_uint(f);
  u += 0x7fffu + ((u >> 16) & 1u);   // RNE (finite inputs only)
  return (unsigned short)(u >> 16);
}

// pack two f32 -> two bf16 (round-half-up) in 3 VALU: 2 adds + v_perm_b32.
__device__ __forceinline__ u32 pkbf(float lo, float hi){
  u32 a = __float_as_uint(lo) + 0x8000u;
  u32 b = __float_as_uint(hi) + 0x8000u;
  return __builtin_amdgcn_perm(b, a, 0x07060302u);
}

// ---------------- fp32 -> bf16 convert, all 5 tensors in one launch ---------
__global__ void cvt_all(const float* __restrict__ x,  const float* __restrict__ qw,
                        const float* __restrict__ kw, const float* __restrict__ vw,
                        const float* __restrict__ ow,
                        unsigned short* __restrict__ xb,  unsigned short* __restrict__ wqb,
                        unsigned short* __restrict__ wkb, unsigned short* __restrict__ wvb,
                        unsigned short* __restrict__ wob,
                        int n4x, int n4w){
  int i = blockIdx.x * 256 + threadIdx.x;
  const float* src; unsigned short* dst; int n4;
  switch (blockIdx.y) {
    case 0:  src = x;  dst = xb;  n4 = n4x; break;
    case 1:  src = qw; dst = wqb; n4 = n4w; break;
    case 2:  src = kw; dst = wkb; n4 = n4w; break;
    case 3:  src = vw; dst = wvb; n4 = n4w; break;
    default: src = ow; dst = wob; n4 = n4w; break;
  }
  if (i >= n4) return;
  float4 f = reinterpret_cast<const float4*>(src)[i];
  ushort4 u;
  u.x = f2bf(f.x); u.y = f2bf(f.y); u.z = f2bf(f.z); u.w = f2bf(f.w);
  reinterpret_cast<ushort4*>(dst)[i] = u;
}

// ---------------- FUSED QKV projection (one pass over X) --------------------
// One block computes the 128x64 output tile for ALL THREE projections:
// stages its X-tile ONCE + Wq/Wk/Wv tiles.  Per K-step per wave: 48 MFMA,
// 20 ds_read_b128, 10 global_load_lds (vs 3x(16,12,6) for the split form).
// LDS 80 KB -> 2 blocks/CU; grid 512 = exactly one residency round.
// Chunk-XOR swizzle (conflict-free, verified R1) + depth-2 counted-vmcnt
// pipeline (verified R2): no vmcnt(0) drain in steady state.
struct FragsQKV { short8 a0[4], a1[4], b0[3][2], b1[3][2]; };

__global__ __launch_bounds__(256, 2) void gemm_qkv(
    const unsigned short* __restrict__ X,
    const unsigned short* __restrict__ Wq,
    const unsigned short* __restrict__ Wk,
    const unsigned short* __restrict__ Wv,
    unsigned short* __restrict__ Qo,
    unsigned short* __restrict__ Ko,
    unsigned short* __restrict__ Vo)
{
  const int n0 = blockIdx.x * 64;
  const int m0 = blockIdx.y * 128;

  __shared__ unsigned short As[2][128 * 64];      // 2 x 16 KiB
  __shared__ unsigned short Bs[2][3][64 * 64];    // 2 x 3 x 8 KiB

  const int tid  = threadIdx.x;
  const int wid  = tid >> 6, lane = tid & 63;
  const int wm   = (wid >> 1) * 64, wn = (wid & 1) * 32;
  const int lr   = lane & 15, c = lane >> 4;
  const int sw   = lr & 7;
  const int pc0  = (c ^ sw) * 8;               // k-half 0 chunk, shorts
  const int pc1  = ((c ^ 4) ^ sw) * 8;         // k-half 1 chunk, shorts

  const int srow = lane >> 3;                  // 0..7
  const int scol = ((lane & 7) ^ srow) * 8;    // inverse-swizzled source col
  const unsigned short* gA  = X  + (size_t)(m0 + wid * 32 + srow) * KDIM + scol;
  const unsigned short* gBq = Wq + (size_t)(n0 + wid * 16 + srow) * KDIM + scol;
  const unsigned short* gBk = Wk + (size_t)(n0 + wid * 16 + srow) * KDIM + scol;
  const unsigned short* gBv = Wv + (size_t)(n0 + wid * 16 + srow) * KDIM + scol;

  auto stage = [&](int buf, int k0) {
    unsigned short* la  = &As[buf][(wid * 32) * 64];
    unsigned short* lbq = &Bs[buf][0][(wid * 16) * 64];
    unsigned short* lbk = &Bs[buf][1][(wid * 16) * 64];
    unsigned short* lbv = &Bs[buf][2][(wid * 16) * 64];
#pragma unroll
    for (int i = 0; i < 4; i++) gll16(gA + (size_t)(i * 8) * KDIM + k0, la + i * 512);
#pragma unroll
    for (int i = 0; i < 2; i++) gll16(gBq + (size_t)(i * 8) * KDIM + k0, lbq + i * 512);
#pragma unroll
    for (int i = 0; i < 2; i++) gll16(gBk + (size_t)(i * 8) * KDIM + k0, lbk + i * 512);
#pragma unroll
    for (int i = 0; i < 2; i++) gll16(gBv + (size_t)(i * 8) * KDIM + k0, lbv + i * 512);
  };

  auto ldfr = [&](int buf, FragsQKV& f) {
    const unsigned short* AS = As[buf];
#pragma unroll
    for (int i = 0; i < 4; i++) {
      f.a0[i] = *(const short8*)&AS[(wm + i * 16 + lr) * 64 + pc0];
      f.a1[i] = *(const short8*)&AS[(wm + i * 16 + lr) * 64 + pc1];
    }
#pragma unroll
    for (int z = 0; z < 3; z++) {
      const unsigned short* BS = Bs[buf][z];
#pragma unroll
      for (int j = 0; j < 2; j++) {
        f.b0[z][j] = *(const short8*)&BS[(wn + j * 16 + lr) * 64 + pc0];
        f.b1[z][j] = *(const short8*)&BS[(wn + j * 16 + lr) * 64 + pc1];
      }
    }
  };

  f32x4 acc[3][4][2];
  const f32x4 z4 = {0.f, 0.f, 0.f, 0.f};
#pragma unroll
  for (int z = 0; z < 3; z++)
    for (int i = 0; i < 4; i++)
      for (int j = 0; j < 2; j++) acc[z][i][j] = z4;

  auto mfmas = [&](const FragsQKV& f) {
#pragma unroll
    for (int z = 0; z < 3; z++) {
      if (z == 2) {
#pragma unroll
        for (int i = 0; i < 4; i++)
#pragma unroll
          for (int j = 0; j < 2; j++) {
            acc[z][i][j] = MFMA(f.b0[z][j], f.a0[i], acc[z][i][j]);  // V: rows=W-dim
            acc[z][i][j] = MFMA(f.b1[z][j], f.a1[i], acc[z][i][j]);
          }
      } else {
#pragma unroll
        for (int i = 0; i < 4; i++)
#pragma unroll
          for (int j = 0; j < 2; j++) {
            acc[z][i][j] = MFMA(f.a0[i], f.b0[z][j], acc[z][i][j]);
            acc[z][i][j] = MFMA(f.a1[i], f.b1[z][j], acc[z][i][j]);
          }
      }
    }
  };

  // prologue: two tiles in flight (20 loads)
  stage(0, 0);
  stage(1, 64);

  FragsQKV f;
  const int NT = KDIM / 64;                    // 16
  for (int t = 0; t < NT - 2; ++t) {
    const int buf = t & 1;
    asm volatile("s_waitcnt vmcnt(10)" ::: "memory");  // my stage(t) landed
    __builtin_amdgcn_s_barrier();                       // everyone's landed
    asm volatile("" ::: "memory");
    ldfr(buf, f);
    asm volatile("s_waitcnt lgkmcnt(0)" ::: "memory"); // my reads serviced
    __builtin_amdgcn_sched_barrier(0);
    __builtin_amdgcn_s_barrier();                       // buf free to overwrite
    asm volatile("" ::: "memory");
    stage(buf, (t + 2) * 64);                           // 10 loads in flight
    __builtin_amdgcn_sched_barrier(0);
    mfmas(f);                                           // covers load latency
  }
  // t = NT-2: no further staging
  asm volatile("s_waitcnt vmcnt(10)" ::: "memory");
  __builtin_amdgcn_s_barrier();
  asm volatile("" ::: "memory");
  ldfr((NT - 2) & 1, f);
  mfmas(f);
  // t = NT-1: drain the last tile
  asm volatile("s_waitcnt vmcnt(0)" ::: "memory");
  __builtin_amdgcn_s_barrier();
  asm volatile("" ::: "memory");
  ldfr((NT - 1) & 1, f);
  mfmas(f);

  const int rbase = (lane >> 4) * 4;
  // z=0: Q (scaled), z=1: K, z=2: V^T
  for (int i = 0; i < 4; i++)
    for (int j = 0; j < 2; j++)
      for (int r = 0; r < 4; r++) {
        int m = m0 + wm + i * 16 + rbase + r;
        int n = n0 + wn + j * 16 + lr;
        int bb = m >> 11, s = m & 2047, h = n >> 6, d = n & 63;
        float vq = acc[0][i][j][r] * 0.18033688f;  // (1/sqrt(64))*log2(e)
        Qo[(((bb * H_ + h) * S_) + s) * DK + d] = f2bf(vq);
        Ko[(((bb * H_ + h) * S_) + s) * DK + d] = f2bf(acc[1][i][j][r]);
      }
  for (int i = 0; i < 4; i++)
    for (int j = 0; j < 2; j++)
      for (int r = 0; r < 4; r++) {
        int dfull = n0 + wn + j * 16 + rbase + r;   // W row (h,dk)
        int sfull = m0 + wm + i * 16 + lr;          // X row (b,s)
        int h = dfull >> 6, d = dfull & 63;
        int bb = sfull >> 11, s = sfull & 2047;
        Vo[(((bb * H_ + h) * DK) + d) * S_ + s] = f2bf(acc[2][i][j][r]);
      }
}

// ---------------- causal flash attention (R9 structure + setprio) -----------
// Q,K: [B,H,S,DK] bf16 (Q pre-scaled to exp2 domain); V: [B,H,DK,S] bf16.
// K/V staged via global_load_lds into UNPADDED 64x64 tiles with a rotation
// swizzle: physical 16B-chunk c of row r holds logical chunk (c-r)&7.
// Ping-pong buffers, 1 barrier per tile, no reg round-trip.
// T5: s_setprio(1) around MFMA clusters (attn-positive per wave role split).
__global__ __launch_bounds__(512, 4) void attn(
    const unsigned short* __restrict__ Q,
    const unsigned short* __restrict__ K,
    const unsigned short* __restrict__ V,
    unsigned short* __restrict__ O)
{
  const int h = blockIdx.y, b = blockIdx.z;
  const int qt = b ? (15 - blockIdx.x) : blockIdx.x;

  const unsigned short* __restrict__ Qh = Q + (size_t)((b * H_ + h) * S_) * DK;
  const unsigned short* __restrict__ Kh = K + (size_t)((b * H_ + h) * S_) * DK;
  const unsigned short* __restrict__ Vh = V + (size_t)((b * H_ + h) * DK) * S_;

  __shared__ unsigned short Ks0[64 * 64];     // [key][d], swizzled chunks
  __shared__ unsigned short Ks1[64 * 64];
  __shared__ unsigned short Vs0[64 * 64];     // [d][key], swizzled chunks
  __shared__ unsigned short Vs1[64 * 64];
  __shared__ unsigned short Ps[8][16][72];    // per-wave: [q][key] (padded)

  const int tid = threadIdx.x, wid = tid >> 6, lane = tid & 63;
  const int lr = lane & 15;
  const int row4 = (lane >> 4) * 4;
  const int q0 = qt * 128;
  const int qcol = q0 + wid * 16 + lr;
  const int qwmin = q0 + wid * 16;
  const int qwmax = qwmin + 15;
  const int lk = (lane >> 4) * 8;             // for Q/P fragments (unswizzled)

  // swizzled LDS read offsets (shorts): logical chunk q=(lane>>4), rot by row
  const int pc0 = (((lane >> 4) + lr) & 7) * 8;
  const int pc1 = (((lane >> 4) + 4 + lr) & 7) * 8;

  // staging: wave wid covers rows [8*wid, 8*wid+8) of both K and V tiles
  const int sr8 = lane >> 3;                  // 0..7 row within chunk
  const int sc8 = lane & 7;                   // physical chunk
  const int sg  = (sc8 - sr8) & 7;            // logical chunk to fetch
  const int stRow = wid * 8 + sr8;            // 0..63
  const unsigned short* gK = Kh + (size_t)stRow * DK + sg * 8;
  const unsigned short* gV = Vh + (size_t)stRow * S_ + sg * 8;
  unsigned short* lK0 = &Ks0[wid * 8 * 64];
  unsigned short* lK1 = &Ks1[wid * 8 * 64];
  unsigned short* lV0 = &Vs0[wid * 8 * 64];
  unsigned short* lV1 = &Vs1[wid * 8 * 64];

  const short ONE = (short)0x3F80;            // bf16 1.0
  const short8 ones = {ONE, ONE, ONE, ONE, ONE, ONE, ONE, ONE};

  short8 qf[2];
  qf[0] = *(const short8*)&Qh[(q0 + wid * 16 + lr) * DK + lk];
  qf[1] = *(const short8*)&Qh[(q0 + wid * 16 + lr) * DK + 32 + lk];

  const f32x4 z4 = {0.f, 0.f, 0.f, 0.f};
  f32x4 o[4];
  for (int i = 0; i < 4; i++) o[i] = z4;
  f32x4 rs = z4;                              // l(q=lr) on the MFMA pipe

  auto tile = [&](int k0, const unsigned short* KS, const unsigned short* VS){
    if (k0 > qwmax) return;                   // wave-uniform skip
    f32x4 sc[4];
    __builtin_amdgcn_s_setprio(1);
    for (int nt = 0; nt < 4; nt++) {
      short8 kb0 = *(const short8*)&KS[(nt * 16 + lr) * 64 + pc0];
      short8 kb1 = *(const short8*)&KS[(nt * 16 + lr) * 64 + pc1];
      f32x4 s = MFMA(kb0, qf[0], z4);
      sc[nt] = MFMA(kb1, qf[1], s);
    }
    __builtin_amdgcn_s_setprio(0);
    if (k0 + 63 > qwmin) {                    // diagonal region: mask key > q
      for (int nt = 0; nt < 4; nt++) {
        int kg = k0 + nt * 16 + row4;
        for (int r = 0; r < 4; r++)
          if (kg + r > qcol) sc[nt][r] = -INFINITY;
      }
    }
    for (int nt = 0; nt < 4; nt++) {
      float p0 = __builtin_amdgcn_exp2f(sc[nt][0]);
      float p1 = __builtin_amdgcn_exp2f(sc[nt][1]);
      float p2 = __builtin_amdgcn_exp2f(sc[nt][2]);
      float p3 = __builtin_amdgcn_exp2f(sc[nt][3]);
      uint2 pk;
      pk.x = pkbf(p0, p1);
      pk.y = pkbf(p2, p3);
      *(uint2*)&Ps[wid][lr][nt * 16 + row4] = pk;
    }
    short8 pf0 = *(const short8*)&Ps[wid][lr][lk];
    short8 pf1 = *(const short8*)&Ps[wid][lr][32 + lk];
    __builtin_amdgcn_s_setprio(1);
    rs = MFMA(ones, pf0, rs);
    rs = MFMA(ones, pf1, rs);
    for (int dt = 0; dt < 4; dt++) {
      short8 vb0 = *(const short8*)&VS[(dt * 16 + lr) * 64 + pc0];
      short8 vb1 = *(const short8*)&VS[(dt * 16 + lr) * 64 + pc1];
      o[dt] = MFMA(vb0, pf0, o[dt]);
      o[dt] = MFMA(vb1, pf1, o[dt]);
    }
    __builtin_amdgcn_s_setprio(0);
  };

  const int kt_end = 2 * qt + 2;              // even

  // prologue: tile 0 into buf0
  gll16(gK, lK0);
  gll16(gV, lV0);

  for (int kt = 0; kt < kt_end; kt += 2) {
    const int k0 = kt * 64;
    __syncthreads();                          // buf0 (k0) ready
    {                                         // kt+1 always < kt_end
      gll16(gK + (size_t)(k0 + 64) * DK, lK1);
      gll16(gV + (k0 + 64),              lV1);
    }
    tile(k0, Ks0, Vs0);
    __syncthreads();                          // buf1 (k0+64) ready
    if (kt + 2 < kt_end) {
      gll16(gK + (size_t)(k0 + 128) * DK, lK0);
      gll16(gV + (k0 + 128),              lV0);
    }
    tile(k0 + 64, Ks1, Vs1);
  }

  const float inv = 1.0f / rs[0];

  const int srow = q0 + wid * 16 + lr;
  for (int dt = 0; dt < 4; dt++) {
    uint2 pk;
    pk.x = pkbf(o[dt][0] * inv, o[dt][1] * inv);
    pk.y = pkbf(o[dt][2] * inv, o[dt][3] * inv);
    *(uint2*)&O[(size_t)(b * S_ + srow) * D_ + h * DK + dt * 16 + row4] = pk;
  }
}

struct Frags { short8 a0[4], a1[4], b0[2], b1[2]; };

// ---------------- output projection (counted-vmcnt pipeline, fp32 out) ------
__global__ __launch_bounds__(256) void gemm_oproj(
    const unsigned short* __restrict__ A,
    const unsigned short* __restrict__ W,
    float* __restrict__ out)
{
  const int n0 = blockIdx.x * 64;
  const int m0 = blockIdx.y * 128;

  __shared__ unsigned short As[2][128 * 64];
  __shared__ unsigned short Bs[2][64 * 64];

  const int tid  = threadIdx.x;
  const int wid  = tid >> 6, lane = tid & 63;
  const int wm   = (wid >> 1) * 64, wn = (wid & 1) * 32;
  const int lr   = lane & 15, c = lane >> 4;
  const int sw   = lr & 7;
  const int pc0  = (c ^ sw) * 8;
  const int pc1  = ((c ^ 4) ^ sw) * 8;

  const int srow = lane >> 3;
  const int scol = ((lane & 7) ^ srow) * 8;
  const unsigned short* gA = A + (size_t)(m0 + wid * 32 + srow) * KDIM + scol;
  const unsigned short* gB = W + (size_t)(n0 + wid * 16 + srow) * KDIM + scol;

  auto stage = [&](int buf, int k0) {
    unsigned short* la = &As[buf][(wid * 32) * 64];
    unsigned short* lb = &Bs[buf][(wid * 16) * 64];
#pragma unroll
    for (int i = 0; i < 4; i++) gll16(gA + (size_t)(i * 8) * KDIM + k0, la + i * 512);
#pragma unroll
    for (int i = 0; i < 2; i++) gll16(gB + (size_t)(i * 8) * KDIM + k0, lb + i * 512);
  };

  auto ldfr = [&](int buf, Frags& f) {
    const unsigned short* AS = As[buf];
    const unsigned short* BS = Bs[buf];
#pragma unroll
    for (int i = 0; i < 4; i++) {
      f.a0[i] = *(const short8*)&AS[(wm + i * 16 + lr) * 64 + pc0];
      f.a1[i] = *(const short8*)&AS[(wm + i * 16 + lr) * 64 + pc1];
    }
#pragma unroll
    for (int j = 0; j < 2; j++) {
      f.b0[j] = *(const short8*)&BS[(wn + j * 16 + lr) * 64 + pc0];
      f.b1[j] = *(const short8*)&BS[(wn + j * 16 + lr) * 64 + pc1];
    }
  };

  f32x4 acc[4][2];
  const f32x4 z4 = {0.f, 0.f, 0.f, 0.f};
  for (int i = 0; i < 4; i++)
    for (int j = 0; j < 2; j++) acc[i][j] = z4;

  auto mfmas = [&](const Frags& f) {
#pragma unroll
    for (int i = 0; i < 4; i++)
#pragma unroll
      for (int j = 0; j < 2; j++) {
        acc[i][j] = MFMA(f.a0[i], f.b0[j], acc[i][j]);
        acc[i][j] = MFMA(f.a1[i], f.b1[j], acc[i][j]);
      }
  };

  stage(0, 0);
  stage(1, 64);

  Frags f;
  const int NT = KDIM / 64;                    // 16
  for (int t = 0; t < NT - 2; ++t) {
    const int buf = t & 1;
    asm volatile("s_waitcnt vmcnt(6)" ::: "memory");
    __builtin_amdgcn_s_barrier();
    asm volatile("" ::: "memory");
    ldfr(buf, f);
    asm volatile("s_waitcnt lgkmcnt(0)" ::: "memory");
    __builtin_amdgcn_sched_barrier(0);
    __builtin_amdgcn_s_barrier();
    asm volatile("" ::: "memory");
    stage(buf, (t + 2) * 64);
    __builtin_amdgcn_sched_barrier(0);
    mfmas(f);
  }
  asm volatile("s_waitcnt vmcnt(6)" ::: "memory");
  __builtin_amdgcn_s_barrier();
  asm volatile("" ::: "memory");
  ldfr((NT - 2) & 1, f);
  mfmas(f);
  asm volatile("s_waitcnt vmcnt(0)" ::: "memory");
  __builtin_amdgcn_s_barrier();
  asm volatile("" ::: "memory");
  ldfr((NT - 1) & 1, f);
  mfmas(f);

  const int rbase = (lane >> 4) * 4;
  for (int i = 0; i < 4; i++)
    for (int j = 0; j < 2; j++)
      for (int r = 0; r < 4; r++) {
        int m = m0 + wm + i * 16 + rbase + r;
        int n = n0 + wn + j * 16 + lr;
        out[(size_t)m * D_ + n] = acc[i][j][r];
      }
}

extern "C" void kernel_launch(void* const* d_in, const int* in_sizes, int n_in,
                              void* d_out, int out_size, void* d_ws, size_t ws_size,
                              hipStream_t stream) {
  const float* x  = (const float*)d_in[0];
  const float* qw = (const float*)d_in[1];
  const float* kw = (const float*)d_in[2];
  const float* vw = (const float*)d_in[3];
  const float* ow = (const float*)d_in[4];
  float* out = (float*)d_out;

  char* ws = (char*)d_ws;
  size_t off = 0;
  auto alloc = [&](size_t bytes) -> void* {
    void* p = ws + off;
    off += (bytes + 255) & ~(size_t)255;
    return p;
  };
  const size_t XN = (size_t)B_ * S_ * D_;     // 4194304
  const size_t WN = (size_t)D_ * D_;          // 1048576
  unsigned short* xb  = (unsigned short*)alloc(XN * 2);
  unsigned short* wqb = (unsigned short*)alloc(WN * 2);
  unsigned short* wkb = (unsigned short*)alloc(WN * 2);
  unsigned short* wvb = (unsigned short*)alloc(WN * 2);
  unsigned short* wob = (unsigned short*)alloc(WN * 2);
  unsigned short* Qb  = (unsigned short*)alloc(XN * 2);
  unsigned short* Kb  = (unsigned short*)alloc(XN * 2);
  unsigned short* Vb  = (unsigned short*)alloc(XN * 2);
  unsigned short* Ob  = (unsigned short*)alloc(XN * 2);

  cvt_all<<<dim3((XN / 4 + 255) / 256, 5), dim3(256), 0, stream>>>(
      x, qw, kw, vw, ow, xb, wqb, wkb, wvb, wob, (int)(XN / 4), (int)(WN / 4));

  gemm_qkv<<<dim3(D_ / 64, (B_ * S_) / 128), dim3(256), 0, stream>>>(
      xb, wqb, wkb, wvb, Qb, Kb, Vb);

  attn<<<dim3(S_ / 128, H_, B_), dim3(512), 0, stream>>>(Qb, Kb, Vb, Ob);

  gemm_oproj<<<dim3(D_ / 64, (B_ * S_) / 128), dim3(256), 0, stream>>>(Ob, wob, out);
}